// Round 1
// baseline (227.474 us; speedup 1.0000x reference)
//
#include <hip/hip_runtime.h>
#include <cstdint>

// ExcitationShaper: segment-averaged params -> sigmoid/logspace maps -> gain ->
// fractional pluck comb -> time-varying RBJ low-pass biquad (TDF-II).
// Biquad parallelized as a blocked affine scan (2x2 matrix + vector compose).

namespace {
constexpr int B = 32;
constexpr int T = 65536;
constexpr int MAXSEG = 2048;      // >> expected ~66 onsets/row (p=1e-3)
constexpr int L = 512;            // samples per scan chunk
constexpr int NC = T / L;         // 128 chunks per row
constexpr int NCHT = B * NC;      // 4096 total chunks
constexpr int WV = 64;            // onset-count waves per row
constexpr int SPAN = T / WV;      // 1024 samples per wave

constexpr float MIN_W_C  = 0.00785398163397448279f; // 2*pi*20/16000 = pi/400
constexpr float LOG2_400 = 8.64385618977472436f;    // log2(pi / MIN_W)
constexpr float LOG2_20  = 4.32192809488736235f;    // log2(2.0/0.1)

__device__ __forceinline__ float rcpf(float v) { return __builtin_amdgcn_rcpf(v); }
__device__ __forceinline__ float sigmoidf(float v) {
  return rcpf(1.f + __expf(-v));
}
} // namespace

// ---- K1: count onsets per (row, wave-span) via ballot ----
__global__ void k_count(const int* __restrict__ onsets, int* __restrict__ cnt) {
  int gw = (blockIdx.x * blockDim.x + threadIdx.x) >> 6;
  int lane = threadIdx.x & 63;
  int b = gw / WV, wv = gw % WV;
  const int* po = onsets + b * T + wv * SPAN;
  int run = 0;
  for (int it = 0; it < SPAN / 64; ++it) {
    int o = po[it * 64 + lane];
    unsigned long long m = __ballot(o != 0);
    run += __popcll(m);
  }
  if (lane == 0) cnt[b * WV + wv] = run;
}

// ---- K2: exclusive scan of span counts per row (tiny) ----
__global__ void k_scanbase(const int* __restrict__ cnt, int* __restrict__ basep,
                           int* __restrict__ nseg) {
  int b = threadIdx.x;
  if (b < B) {
    int run = 0;
    for (int c = 0; c < WV; ++c) { basep[b * WV + c] = run; run += cnt[b * WV + c]; }
    nseg[b] = run;  // total onsets; segments = run+1
  }
}

// ---- K3: inclusive cumsum -> seg ids; record onset positions ----
__global__ void k_segids(const int* __restrict__ onsets, const int* __restrict__ basep,
                         int* __restrict__ seg_ids, int* __restrict__ onsetPos) {
  int gw = (blockIdx.x * blockDim.x + threadIdx.x) >> 6;
  int lane = threadIdx.x & 63;
  int b = gw / WV, wv = gw % WV;
  const int rb = b * T;
  int t0 = wv * SPAN;
  int run = basep[b * WV + wv];
  unsigned long long bm = (1ull << lane) - 1ull;
  for (int it = 0; it < SPAN / 64; ++it) {
    int t = t0 + it * 64 + lane;
    int o = onsets[rb + t] != 0;
    unsigned long long m = __ballot(o);
    int sid = run + __popcll(m & bm) + o;   // inclusive cumsum
    seg_ids[rb + t] = sid;
    if (o && sid <= MAXSEG) onsetPos[b * MAXSEG + sid - 1] = t;
    run += __popcll(m);
  }
}

// ---- K4: per-segment average of the 4 param channels ----
__global__ void k_segavg(const float* __restrict__ params, const int* __restrict__ onsetPos,
                         const int* __restrict__ nseg, float4* __restrict__ avg) {
  __shared__ float part[4][4];
  int b = blockIdx.x >> 6;   // 64 blocks grid-stride over segments per row
  int s0 = blockIdx.x & 63;
  int n = nseg[b];
  int tid = threadIdx.x;
  const float4* pp = (const float4*)params;  // [B][T] float4
  for (int s = s0; s <= n; s += 64) {
    int start = (s == 0) ? 0 : onsetPos[b * MAXSEG + min(s, MAXSEG) - 1];
    int end   = (s == n) ? T : onsetPos[b * MAXSEG + min(s, MAXSEG - 1)];
    float a0 = 0.f, a1 = 0.f, a2 = 0.f, a3 = 0.f;
    for (int t = start + tid; t < end; t += 256) {
      float4 pv = pp[b * T + t];
      a0 += pv.x; a1 += pv.y; a2 += pv.z; a3 += pv.w;
    }
    for (int off = 32; off; off >>= 1) {
      a0 += __shfl_down(a0, off); a1 += __shfl_down(a1, off);
      a2 += __shfl_down(a2, off); a3 += __shfl_down(a3, off);
    }
    if ((tid & 63) == 0) {
      int w = tid >> 6;
      part[w][0] = a0; part[w][1] = a1; part[w][2] = a2; part[w][3] = a3;
    }
    __syncthreads();
    if (tid == 0) {
      float t0 = 0.f, t1 = 0.f, t2 = 0.f, t3 = 0.f;
      for (int w = 0; w < 4; ++w) {
        t0 += part[w][0]; t1 += part[w][1]; t2 += part[w][2]; t3 += part[w][3];
      }
      float inv = 1.0f / (float)max(end - start, 1);
      avg[b * MAXSEG + min(s, MAXSEG - 1)] = make_float4(t0 * inv, t1 * inv, t2 * inv, t3 * inv);
    }
    __syncthreads();
  }
}

// ---- K5: per-sample coefficients + comb; write transposed [b][j][c] via LDS tile ----
__global__ void k_coef(const float* __restrict__ f0, const float* __restrict__ x,
                       const int* __restrict__ seg_ids, const float4* __restrict__ avg,
                       float* __restrict__ p0g, float* __restrict__ ca1g,
                       float* __restrict__ ca2g) {
  __shared__ float ls[3][64][65];  // +1 pad: conflict-free transpose
  int b = blockIdx.x >> 4;
  int tile = blockIdx.x & 15;
  int jt = tile & 7, ct = tile >> 3;  // 8 j-tiles x 2 c-tiles of 64
  int tid = threadIdx.x;
  const int rb = b * T;
  for (int it = 0; it < 16; ++it) {
    int lin = it * 256 + tid;
    int jj = lin & 63, cc = lin >> 6;           // jj fastest -> coalesced t reads
    int t = (ct * 64 + cc) * L + (jt * 64 + jj);
    int sid = min(seg_ids[rb + t], MAXSEG - 1);
    float4 av = avg[b * MAXSEG + sid];
    float dist = 0.1f * exp2f(sigmoidf(av.x) * LOG2_20);
    float mu = sigmoidf(av.w);
    float p = f0[rb + t] * mu;
    float z = floorf(p);
    float alfa = p - z;
    int i1 = t - (int)z - 1;
    int i2 = i1 - 1;
    float xl1 = 0.f, xl2 = 0.f;
    if (i1 >= 0) {
      int s1i = min(seg_ids[rb + i1], MAXSEG - 1);
      xl1 = x[rb + i1] * (0.1f * exp2f(sigmoidf(avg[b * MAXSEG + s1i].x) * LOG2_20));
    }
    if (i2 >= 0) {
      int s2i = min(seg_ids[rb + i2], MAXSEG - 1);
      xl2 = x[rb + i2] * (0.1f * exp2f(sigmoidf(avg[b * MAXSEG + s2i].x) * LOG2_20));
    }
    float xc = x[rb + t] * dist - (1.f - alfa) * xl1 - alfa * xl2;
    float wv = MIN_W_C * exp2f(sigmoidf(av.y) * LOG2_400);
    float qv = 0.1f * exp2f(sigmoidf(av.z) * LOG2_20);
    float sw = __sinf(wv), cw = __cosf(wv);
    float alpha = sw * 0.5f * rcpf(qv);
    float ra0 = rcpf(1.f + alpha);
    float b0 = 0.5f * (1.f - cw) * ra0;
    ls[0][cc][jj] = b0 * xc;           // p0
    ls[1][cc][jj] = 2.f * cw * ra0;    // -a1
    ls[2][cc][jj] = (alpha - 1.f) * ra0; // -a2
  }
  __syncthreads();
  for (int it = 0; it < 16; ++it) {
    int lin = it * 256 + tid;
    int cc = lin & 63, jj = lin >> 6;           // cc fastest -> coalesced u writes
    int u = rb + (jt * 64 + jj) * NC + (ct * 64 + cc);
    p0g[u] = ls[0][cc][jj];
    ca1g[u] = ls[1][cc][jj];
    ca2g[u] = ls[2][cc][jj];
  }
}

// ---- C1: compose per-chunk affine transform ----
__global__ void k_compose(const float* __restrict__ p0g, const float* __restrict__ ca1g,
                          const float* __restrict__ ca2g, float* __restrict__ ctb) {
  int g = blockIdx.x * blockDim.x + threadIdx.x;  // 0..NCHT-1
  int b = g >> 7, c = g & (NC - 1);
  int idx = b * T + c;
  float A00 = 1.f, A01 = 0.f, A10 = 0.f, A11 = 0.f, d0 = 0.f, d1 = 0.f;
#pragma unroll 8
  for (int j = 0; j < L; ++j, idx += NC) {
    float p0 = p0g[idx], na1 = ca1g[idx], na2 = ca2g[idx];
    float c0 = p0 * (2.f + na1);
    float c1 = p0 * (1.f + na2);
    float nA00 = fmaf(na1, A00, A10);
    float nA01 = fmaf(na1, A01, A11);
    float nd0  = fmaf(na1, d0, d1 + c0);
    float nA10 = na2 * A00;
    float nA11 = na2 * A01;
    float nd1  = fmaf(na2, d0, c1);
    A00 = nA00; A01 = nA01; A10 = nA10; A11 = nA11; d0 = nd0; d1 = nd1;
  }
  ctb[0 * NCHT + g] = A00; ctb[1 * NCHT + g] = A01;
  ctb[2 * NCHT + g] = A10; ctb[3 * NCHT + g] = A11;
  ctb[4 * NCHT + g] = d0;  ctb[5 * NCHT + g] = d1;
}

// ---- C2: per-row serial scan over chunk transforms (initial state = 0) ----
__global__ void k_scanrows(const float* __restrict__ ctb, float* __restrict__ S1,
                           float* __restrict__ S2) {
  __shared__ float lds[6][NC];
  __shared__ float ls1[NC], ls2[NC];
  int b = blockIdx.x;
  int tid = threadIdx.x;  // 64
  for (int k = 0; k < 6; ++k)
    for (int i = tid; i < NC; i += 64) lds[k][i] = ctb[k * NCHT + b * NC + i];
  __syncthreads();
  if (tid == 0) {
    float s1 = 0.f, s2 = 0.f;
    for (int c = 0; c < NC; ++c) {
      ls1[c] = s1; ls2[c] = s2;
      float t1 = fmaf(lds[0][c], s1, fmaf(lds[1][c], s2, lds[4][c]));
      float t2 = fmaf(lds[2][c], s1, fmaf(lds[3][c], s2, lds[5][c]));
      s1 = t1; s2 = t2;
    }
  }
  __syncthreads();
  for (int i = tid; i < NC; i += 64) {
    S1[b * NC + i] = ls1[i];
    S2[b * NC + i] = ls2[i];
  }
}

// ---- C3: re-apply recurrence from known chunk-start state, emit y ----
__global__ void k_apply(const float* __restrict__ p0g, const float* __restrict__ ca1g,
                        const float* __restrict__ ca2g, const float* __restrict__ S1,
                        const float* __restrict__ S2, float* __restrict__ out) {
  int g = blockIdx.x * blockDim.x + threadIdx.x;
  int b = g >> 7, c = g & (NC - 1);
  float s1 = S1[g], s2 = S2[g];
  int idx = b * T + c;
  float* po = out + b * T + c * L;
#pragma unroll 2
  for (int j0 = 0; j0 < L; j0 += 4) {
    float4 yv;
    {
      float p0 = p0g[idx], na1 = ca1g[idx], na2 = ca2g[idx]; idx += NC;
      float y = p0 + s1; yv.x = y;
      float ns1 = fmaf(na1, y, fmaf(2.f, p0, s2));
      float ns2 = fmaf(na2, y, p0);
      s1 = ns1; s2 = ns2;
    }
    {
      float p0 = p0g[idx], na1 = ca1g[idx], na2 = ca2g[idx]; idx += NC;
      float y = p0 + s1; yv.y = y;
      float ns1 = fmaf(na1, y, fmaf(2.f, p0, s2));
      float ns2 = fmaf(na2, y, p0);
      s1 = ns1; s2 = ns2;
    }
    {
      float p0 = p0g[idx], na1 = ca1g[idx], na2 = ca2g[idx]; idx += NC;
      float y = p0 + s1; yv.z = y;
      float ns1 = fmaf(na1, y, fmaf(2.f, p0, s2));
      float ns2 = fmaf(na2, y, p0);
      s1 = ns1; s2 = ns2;
    }
    {
      float p0 = p0g[idx], na1 = ca1g[idx], na2 = ca2g[idx]; idx += NC;
      float y = p0 + s1; yv.w = y;
      float ns1 = fmaf(na1, y, fmaf(2.f, p0, s2));
      float ns2 = fmaf(na2, y, p0);
      s1 = ns1; s2 = ns2;
    }
    *(float4*)(po + j0) = yv;  // lane-contiguous in t -> L2 merges lines
  }
}

extern "C" void kernel_launch(void* const* d_in, const int* in_sizes, int n_in,
                              void* d_out, int out_size, void* d_ws, size_t ws_size,
                              hipStream_t stream) {
  const float* f0     = (const float*)d_in[0];
  const float* x      = (const float*)d_in[1];
  const float* params = (const float*)d_in[2];
  const int*   onsets = (const int*)d_in[3];
  float* out = (float*)d_out;

  // Workspace carve (~35 MB total; everything read is written in-stream first)
  char* w = (char*)d_ws;
  auto alloc = [&](size_t bytes) -> void* {
    void* p = (void*)w;
    w += (bytes + 255) & ~(size_t)255;
    return p;
  };
  int*    seg_ids  = (int*)alloc(sizeof(int) * B * T);
  int*    cnt      = (int*)alloc(sizeof(int) * B * WV);
  int*    basep    = (int*)alloc(sizeof(int) * B * WV);
  int*    nseg     = (int*)alloc(sizeof(int) * B);
  int*    onsetPos = (int*)alloc(sizeof(int) * B * MAXSEG);
  float4* avg      = (float4*)alloc(sizeof(float4) * B * MAXSEG);
  float*  p0g      = (float*)alloc(sizeof(float) * B * T);
  float*  ca1g     = (float*)alloc(sizeof(float) * B * T);
  float*  ca2g     = (float*)alloc(sizeof(float) * B * T);
  float*  ctb      = (float*)alloc(sizeof(float) * 6 * NCHT);
  float*  S1       = (float*)alloc(sizeof(float) * NCHT);
  float*  S2       = (float*)alloc(sizeof(float) * NCHT);
  (void)in_sizes; (void)n_in; (void)out_size; (void)ws_size;

  k_count   <<<512, 256, 0, stream>>>(onsets, cnt);
  k_scanbase<<<1, 64, 0, stream>>>(cnt, basep, nseg);
  k_segids  <<<512, 256, 0, stream>>>(onsets, basep, seg_ids, onsetPos);
  k_segavg  <<<B * 64, 256, 0, stream>>>(params, onsetPos, nseg, avg);
  k_coef    <<<512, 256, 0, stream>>>(f0, x, seg_ids, avg, p0g, ca1g, ca2g);
  k_compose <<<NCHT / 256, 256, 0, stream>>>(p0g, ca1g, ca2g, ctb);
  k_scanrows<<<B, 64, 0, stream>>>(ctb, S1, S2);
  k_apply   <<<NCHT / 256, 256, 0, stream>>>(p0g, ca1g, ca2g, S1, S2, out);
}

// Round 3
// 171.633 us; speedup vs baseline: 1.3254x; 1.3254x over previous
//
#include <hip/hip_runtime.h>
#include <cstdint>

// ExcitationShaper: segment-averaged params -> sigmoid/logspace maps -> gain ->
// fractional pluck comb -> time-varying RBJ low-pass biquad (TDF-II).
// Biquad parallelized as a blocked affine scan (2x2 matrix + vector compose).
// NOTE: identity init MUST be A00=A11=1 (A11=0 projects the transform rank-1;
// at L=16 the KS scan then compounds norms multiplicatively -> inf*0 -> NaN).

namespace {
constexpr int B = 32;
constexpr int T = 65536;
constexpr int MAXSEG = 2048;      // >> expected ~66 onsets/row (p=1e-3)
constexpr int L = 16;             // samples per scan chunk (small -> parallelism)
constexpr int NC = T / L;         // 4096 chunks per row
constexpr int NCHT = B * NC;      // 131072 total chunks
constexpr int WV = 64;            // onset-count waves per row
constexpr int SPAN = T / WV;      // 1024 samples per wave

constexpr float MIN_W_C  = 0.00785398163397448279f; // 2*pi*20/16000 = pi/400
constexpr float LOG2_400 = 8.64385618977472436f;    // log2(pi / MIN_W)
constexpr float LOG2_20  = 4.32192809488736235f;    // log2(2.0/0.1)

__device__ __forceinline__ float sigmoid_precise(float v) {
  return 1.0f / (1.0f + expf(-v));
}

// Per-sample comb + coef lookup. segc = {mu, b0, -a1, -a2}, segd = dist.
__device__ __forceinline__ float comb_p0(int rb, int rs, int t, float xt, float ft,
                                         int sidt, const float* __restrict__ x,
                                         const int* __restrict__ seg,
                                         const float4* __restrict__ segc,
                                         const float* __restrict__ segd,
                                         float& na1, float& na2) {
  float4 sc = segc[rs + sidt];
  float dist = segd[rs + sidt];
  float p = ft * sc.x;            // fractional pluck position
  float z = floorf(p);
  float alfa = p - z;
  int i1 = t - (int)z - 1;
  int i2 = i1 - 1;
  float xl1 = 0.f, xl2 = 0.f;
  if (i1 >= 0) xl1 = x[rb + i1] * segd[rs + min(seg[rb + i1], MAXSEG - 1)];
  if (i2 >= 0) xl2 = x[rb + i2] * segd[rs + min(seg[rb + i2], MAXSEG - 1)];
  float xc = xt * dist - (1.f - alfa) * xl1 - alfa * xl2;
  na1 = sc.z; na2 = sc.w;
  return sc.y * xc;               // p0 = b0 * xc
}
} // namespace

// ---- K1: count onsets per (row, wave-span) via ballot ----
__global__ void k_count(const int* __restrict__ onsets, int* __restrict__ cnt) {
  int gw = (blockIdx.x * blockDim.x + threadIdx.x) >> 6;
  int lane = threadIdx.x & 63;
  int b = gw / WV, wv = gw % WV;
  const int* po = onsets + b * T + wv * SPAN;
  int run = 0;
  for (int it = 0; it < SPAN / 64; ++it) {
    int o = po[it * 64 + lane];
    unsigned long long m = __ballot(o != 0);
    run += __popcll(m);
  }
  if (lane == 0) cnt[b * WV + wv] = run;
}

// ---- K2: exclusive scan of span counts per row (tiny) ----
__global__ void k_scanbase(const int* __restrict__ cnt, int* __restrict__ basep,
                           int* __restrict__ nseg) {
  int b = threadIdx.x;
  if (b < B) {
    int run = 0;
    for (int c = 0; c < WV; ++c) { basep[b * WV + c] = run; run += cnt[b * WV + c]; }
    nseg[b] = run;  // total onsets; segments = run+1
  }
}

// ---- K3: inclusive cumsum -> seg ids; record onset positions ----
__global__ void k_segids(const int* __restrict__ onsets, const int* __restrict__ basep,
                         int* __restrict__ seg_ids, int* __restrict__ onsetPos) {
  int gw = (blockIdx.x * blockDim.x + threadIdx.x) >> 6;
  int lane = threadIdx.x & 63;
  int b = gw / WV, wv = gw % WV;
  const int rb = b * T;
  int t0 = wv * SPAN;
  int run = basep[b * WV + wv];
  unsigned long long bm = (1ull << lane) - 1ull;
  for (int it = 0; it < SPAN / 64; ++it) {
    int t = t0 + it * 64 + lane;
    int o = onsets[rb + t] != 0;
    unsigned long long m = __ballot(o);
    int sid = run + __popcll(m & bm) + o;   // inclusive cumsum
    seg_ids[rb + t] = sid;
    if (o && sid <= MAXSEG) onsetPos[b * MAXSEG + sid - 1] = t;
    run += __popcll(m);
  }
}

// ---- K4: per-segment average + full coefficient precompute (precise math) ----
__global__ void k_segavg(const float* __restrict__ params, const int* __restrict__ onsetPos,
                         const int* __restrict__ nseg, float4* __restrict__ segc,
                         float* __restrict__ segd) {
  __shared__ float part[4][4];
  int b = blockIdx.x >> 6;   // 64 blocks grid-stride over segments per row
  int s0 = blockIdx.x & 63;
  int n = nseg[b];
  int tid = threadIdx.x;
  const float4* pp = (const float4*)params;  // [B][T] float4
  for (int s = s0; s <= n; s += 64) {
    int start = (s == 0) ? 0 : onsetPos[b * MAXSEG + min(s, MAXSEG) - 1];
    int end   = (s == n) ? T : onsetPos[b * MAXSEG + min(s, MAXSEG - 1)];
    float a0 = 0.f, a1 = 0.f, a2 = 0.f, a3 = 0.f;
    for (int t = start + tid; t < end; t += 256) {
      float4 pv = pp[b * T + t];
      a0 += pv.x; a1 += pv.y; a2 += pv.z; a3 += pv.w;
    }
    for (int off = 32; off; off >>= 1) {
      a0 += __shfl_down(a0, off); a1 += __shfl_down(a1, off);
      a2 += __shfl_down(a2, off); a3 += __shfl_down(a3, off);
    }
    if ((tid & 63) == 0) {
      int w = tid >> 6;
      part[w][0] = a0; part[w][1] = a1; part[w][2] = a2; part[w][3] = a3;
    }
    __syncthreads();
    if (tid == 0) {
      float t0 = 0.f, t1 = 0.f, t2 = 0.f, t3 = 0.f;
      for (int w = 0; w < 4; ++w) {
        t0 += part[w][0]; t1 += part[w][1]; t2 += part[w][2]; t3 += part[w][3];
      }
      float inv = 1.0f / (float)max(end - start, 1);
      float av0 = t0 * inv, av1 = t1 * inv, av2 = t2 * inv, av3 = t3 * inv;
      // precise per-segment mapping (only ~66 segments/row -> cost negligible)
      float dist = 0.1f * exp2f(sigmoid_precise(av0) * LOG2_20);
      float wv   = MIN_W_C * exp2f(sigmoid_precise(av1) * LOG2_400);
      float qv   = 0.1f * exp2f(sigmoid_precise(av2) * LOG2_20);
      float mu   = sigmoid_precise(av3);
      float sw = sinf(wv), cw = cosf(wv);
      float alpha = sw / (2.0f * qv);
      float a0c = 1.0f + alpha;
      float b0 = (1.0f - cw) / (2.0f * a0c);
      float na1 = 2.0f * cw / a0c;          // -a1
      float na2 = (alpha - 1.0f) / a0c;     // -a2
      int sl = min(s, MAXSEG - 1);
      segc[b * MAXSEG + sl] = make_float4(mu, b0, na1, na2);
      segd[b * MAXSEG + sl] = dist;
    }
    __syncthreads();
  }
}

// ---- C1: compose per-chunk (L=16) affine transform, coefs on the fly ----
__global__ void k_compose(const float* __restrict__ f0, const float* __restrict__ x,
                          const int* __restrict__ seg, const float4* __restrict__ segc,
                          const float* __restrict__ segd, float* __restrict__ ctb) {
  int g = blockIdx.x * blockDim.x + threadIdx.x;  // 0..NCHT-1
  int b = g >> 12, c = g & (NC - 1);
  int rb = b * T, rs = b * MAXSEG;
  int t0 = c * L;
  const float4* x4 = (const float4*)(x + rb + t0);
  const float4* f4 = (const float4*)(f0 + rb + t0);
  const int4*   s4 = (const int4*)(seg + rb + t0);
  // PROPER identity: A11 = 1 (A11=0 rank-projects and NaNs the scan)
  float A00 = 1.f, A01 = 0.f, A10 = 0.f, A11 = 1.f, d0 = 0.f, d1 = 0.f;
#pragma unroll
  for (int k = 0; k < 4; ++k) {
    float4 xv = x4[k]; float4 fv = f4[k]; int4 sv = s4[k];
    float xs[4] = {xv.x, xv.y, xv.z, xv.w};
    float fs[4] = {fv.x, fv.y, fv.z, fv.w};
    int   ss[4] = {sv.x, sv.y, sv.z, sv.w};
#pragma unroll
    for (int q = 0; q < 4; ++q) {
      int t = t0 + k * 4 + q;
      float na1, na2;
      float p0 = comb_p0(rb, rs, t, xs[q], fs[q], min(ss[q], MAXSEG - 1),
                         x, seg, segc, segd, na1, na2);
      float c0v = p0 * (2.f + na1);
      float c1v = p0 * (1.f + na2);
      float nA00 = fmaf(na1, A00, A10);
      float nA01 = fmaf(na1, A01, A11);
      float nd0  = fmaf(na1, d0, d1 + c0v);
      float nA10 = na2 * A00;
      float nA11 = na2 * A01;
      float nd1  = fmaf(na2, d0, c1v);
      A00 = nA00; A01 = nA01; A10 = nA10; A11 = nA11; d0 = nd0; d1 = nd1;
    }
  }
  ctb[0 * NCHT + g] = A00; ctb[1 * NCHT + g] = A01;
  ctb[2 * NCHT + g] = A10; ctb[3 * NCHT + g] = A11;
  ctb[4 * NCHT + g] = d0;  ctb[5 * NCHT + g] = d1;
}

// ---- C2: per-row parallel scan over NC=4096 chunk transforms ----
// Block = 256 threads, thread owns 16 contiguous chunks (float4 loads).
__global__ void k_scanrows(const float* __restrict__ ctb, float* __restrict__ S1,
                           float* __restrict__ S2) {
  __shared__ float wagg[4][6];
  int b = blockIdx.x;
  int tid = threadIdx.x;
  int lane = tid & 63, w = tid >> 6;
  int base = b * NC + tid * 16;
  // pass 1: per-thread aggregate over its 16 chunks (in order). Identity init!
  float A00 = 1.f, A01 = 0.f, A10 = 0.f, A11 = 1.f, d0 = 0.f, d1 = 0.f;
#pragma unroll
  for (int k = 0; k < 4; ++k) {
    float4 M00 = *(const float4*)(ctb + 0 * NCHT + base + k * 4);
    float4 M01 = *(const float4*)(ctb + 1 * NCHT + base + k * 4);
    float4 M10 = *(const float4*)(ctb + 2 * NCHT + base + k * 4);
    float4 M11 = *(const float4*)(ctb + 3 * NCHT + base + k * 4);
    float4 E0  = *(const float4*)(ctb + 4 * NCHT + base + k * 4);
    float4 E1  = *(const float4*)(ctb + 5 * NCHT + base + k * 4);
    float m00[4] = {M00.x, M00.y, M00.z, M00.w};
    float m01[4] = {M01.x, M01.y, M01.z, M01.w};
    float m10[4] = {M10.x, M10.y, M10.z, M10.w};
    float m11[4] = {M11.x, M11.y, M11.z, M11.w};
    float e0[4]  = {E0.x, E0.y, E0.z, E0.w};
    float e1[4]  = {E1.x, E1.y, E1.z, E1.w};
#pragma unroll
    for (int q = 0; q < 4; ++q) {
      // result = chunk(q) applied AFTER current prefix
      float nA00 = fmaf(m00[q], A00, m01[q] * A10);
      float nA01 = fmaf(m00[q], A01, m01[q] * A11);
      float nA10 = fmaf(m10[q], A00, m11[q] * A10);
      float nA11 = fmaf(m10[q], A01, m11[q] * A11);
      float nd0  = fmaf(m00[q], d0, fmaf(m01[q], d1, e0[q]));
      float nd1  = fmaf(m10[q], d0, fmaf(m11[q], d1, e1[q]));
      A00 = nA00; A01 = nA01; A10 = nA10; A11 = nA11; d0 = nd0; d1 = nd1;
    }
  }
  // wave-level inclusive Kogge-Stone (compose: first prev-lane, then cur)
#pragma unroll
  for (int off = 1; off < 64; off <<= 1) {
    float P00 = __shfl_up(A00, off), P01 = __shfl_up(A01, off);
    float P10 = __shfl_up(A10, off), P11 = __shfl_up(A11, off);
    float Pd0 = __shfl_up(d0, off),  Pd1 = __shfl_up(d1, off);
    if (lane >= off) {
      float nA00 = fmaf(A00, P00, A01 * P10);
      float nA01 = fmaf(A00, P01, A01 * P11);
      float nA10 = fmaf(A10, P00, A11 * P10);
      float nA11 = fmaf(A10, P01, A11 * P11);
      float nd0  = fmaf(A00, Pd0, fmaf(A01, Pd1, d0));
      float nd1  = fmaf(A10, Pd0, fmaf(A11, Pd1, d1));
      A00 = nA00; A01 = nA01; A10 = nA10; A11 = nA11; d0 = nd0; d1 = nd1;
    }
  }
  if (lane == 63) {
    wagg[w][0] = A00; wagg[w][1] = A01; wagg[w][2] = A10;
    wagg[w][3] = A11; wagg[w][4] = d0;  wagg[w][5] = d1;
  }
  __syncthreads();
  // per-lane exclusive (shift up by 1; lane 0 = identity)
  float E00 = __shfl_up(A00, 1), E01 = __shfl_up(A01, 1);
  float E10 = __shfl_up(A10, 1), E11 = __shfl_up(A11, 1);
  float Ed0 = __shfl_up(d0, 1),  Ed1 = __shfl_up(d1, 1);
  if (lane == 0) { E00 = 1.f; E01 = 0.f; E10 = 0.f; E11 = 1.f; Ed0 = 0.f; Ed1 = 0.f; }
  // exclusive wave prefix: compose waves 0..w-1 in order
  float P00 = 1.f, P01 = 0.f, P10 = 0.f, P11 = 1.f, Pd0 = 0.f, Pd1 = 0.f;
  for (int i = 0; i < w; ++i) {
    float W00 = wagg[i][0], W01 = wagg[i][1], W10 = wagg[i][2];
    float W11 = wagg[i][3], Wd0 = wagg[i][4], Wd1 = wagg[i][5];
    float n00 = fmaf(W00, P00, W01 * P10);
    float n01 = fmaf(W00, P01, W01 * P11);
    float n10 = fmaf(W10, P00, W11 * P10);
    float n11 = fmaf(W10, P01, W11 * P11);
    float nd0 = fmaf(W00, Pd0, fmaf(W01, Pd1, Wd0));
    float nd1 = fmaf(W10, Pd0, fmaf(W11, Pd1, Wd1));
    P00 = n00; P01 = n01; P10 = n10; P11 = n11; Pd0 = nd0; Pd1 = nd1;
  }
  // full exclusive prefix F = E after P; init state = 0 -> chunk-start state = F.d
  float s1 = fmaf(E00, Pd0, fmaf(E01, Pd1, Ed0));
  float s2 = fmaf(E10, Pd0, fmaf(E11, Pd1, Ed1));
  // pass 2: emit chunk-start states for own 16 chunks
#pragma unroll
  for (int k = 0; k < 4; ++k) {
    float4 M00 = *(const float4*)(ctb + 0 * NCHT + base + k * 4);
    float4 M01 = *(const float4*)(ctb + 1 * NCHT + base + k * 4);
    float4 M10 = *(const float4*)(ctb + 2 * NCHT + base + k * 4);
    float4 M11 = *(const float4*)(ctb + 3 * NCHT + base + k * 4);
    float4 E0  = *(const float4*)(ctb + 4 * NCHT + base + k * 4);
    float4 E1  = *(const float4*)(ctb + 5 * NCHT + base + k * 4);
    float m00[4] = {M00.x, M00.y, M00.z, M00.w};
    float m01[4] = {M01.x, M01.y, M01.z, M01.w};
    float m10[4] = {M10.x, M10.y, M10.z, M10.w};
    float m11[4] = {M11.x, M11.y, M11.z, M11.w};
    float e0[4]  = {E0.x, E0.y, E0.z, E0.w};
    float e1[4]  = {E1.x, E1.y, E1.z, E1.w};
    float o1[4], o2[4];
#pragma unroll
    for (int q = 0; q < 4; ++q) {
      o1[q] = s1; o2[q] = s2;
      float t1 = fmaf(m00[q], s1, fmaf(m01[q], s2, e0[q]));
      float t2 = fmaf(m10[q], s1, fmaf(m11[q], s2, e1[q]));
      s1 = t1; s2 = t2;
    }
    *(float4*)(S1 + base + k * 4) = make_float4(o1[0], o1[1], o1[2], o1[3]);
    *(float4*)(S2 + base + k * 4) = make_float4(o2[0], o2[1], o2[2], o2[3]);
  }
}

// ---- C3: re-apply recurrence from chunk-start state, coefs on the fly ----
__global__ void k_apply(const float* __restrict__ f0, const float* __restrict__ x,
                        const int* __restrict__ seg, const float4* __restrict__ segc,
                        const float* __restrict__ segd, const float* __restrict__ S1,
                        const float* __restrict__ S2, float* __restrict__ out) {
  int g = blockIdx.x * blockDim.x + threadIdx.x;
  int b = g >> 12, c = g & (NC - 1);
  int rb = b * T, rs = b * MAXSEG;
  int t0 = c * L;
  const float4* x4 = (const float4*)(x + rb + t0);
  const float4* f4 = (const float4*)(f0 + rb + t0);
  const int4*   s4 = (const int4*)(seg + rb + t0);
  float4* o4 = (float4*)(out + rb + t0);
  float s1 = S1[g], s2 = S2[g];
#pragma unroll
  for (int k = 0; k < 4; ++k) {
    float4 xv = x4[k]; float4 fv = f4[k]; int4 sv = s4[k];
    float xs[4] = {xv.x, xv.y, xv.z, xv.w};
    float fs[4] = {fv.x, fv.y, fv.z, fv.w};
    int   ss[4] = {sv.x, sv.y, sv.z, sv.w};
    float ys[4];
#pragma unroll
    for (int q = 0; q < 4; ++q) {
      int t = t0 + k * 4 + q;
      float na1, na2;
      float p0 = comb_p0(rb, rs, t, xs[q], fs[q], min(ss[q], MAXSEG - 1),
                         x, seg, segc, segd, na1, na2);
      float y = p0 + s1;
      ys[q] = y;
      float ns1 = fmaf(na1, y, fmaf(2.f, p0, s2));
      float ns2 = fmaf(na2, y, p0);
      s1 = ns1; s2 = ns2;
    }
    o4[k] = make_float4(ys[0], ys[1], ys[2], ys[3]);
  }
}

extern "C" void kernel_launch(void* const* d_in, const int* in_sizes, int n_in,
                              void* d_out, int out_size, void* d_ws, size_t ws_size,
                              hipStream_t stream) {
  const float* f0     = (const float*)d_in[0];
  const float* x      = (const float*)d_in[1];
  const float* params = (const float*)d_in[2];
  const int*   onsets = (const int*)d_in[3];
  float* out = (float*)d_out;

  char* w = (char*)d_ws;
  auto alloc = [&](size_t bytes) -> void* {
    void* p = (void*)w;
    w += (bytes + 255) & ~(size_t)255;
    return p;
  };
  int*    seg_ids  = (int*)alloc(sizeof(int) * B * T);
  int*    cnt      = (int*)alloc(sizeof(int) * B * WV);
  int*    basep    = (int*)alloc(sizeof(int) * B * WV);
  int*    nseg     = (int*)alloc(sizeof(int) * B);
  int*    onsetPos = (int*)alloc(sizeof(int) * B * MAXSEG);
  float4* segc     = (float4*)alloc(sizeof(float4) * B * MAXSEG);
  float*  segd     = (float*)alloc(sizeof(float) * B * MAXSEG);
  float*  ctb      = (float*)alloc(sizeof(float) * 6 * NCHT);
  float*  S1       = (float*)alloc(sizeof(float) * NCHT);
  float*  S2       = (float*)alloc(sizeof(float) * NCHT);
  (void)in_sizes; (void)n_in; (void)out_size; (void)ws_size;

  k_count   <<<512, 256, 0, stream>>>(onsets, cnt);
  k_scanbase<<<1, 64, 0, stream>>>(cnt, basep, nseg);
  k_segids  <<<512, 256, 0, stream>>>(onsets, basep, seg_ids, onsetPos);
  k_segavg  <<<B * 64, 256, 0, stream>>>(params, onsetPos, nseg, segc, segd);
  k_compose <<<NCHT / 256, 256, 0, stream>>>(f0, x, seg_ids, segc, segd, ctb);
  k_scanrows<<<B, 256, 0, stream>>>(ctb, S1, S2);
  k_apply   <<<NCHT / 256, 256, 0, stream>>>(f0, x, seg_ids, segc, segd, S1, S2, out);
}

// Round 4
// 141.219 us; speedup vs baseline: 1.6108x; 1.2154x over previous
//
#include <hip/hip_runtime.h>
#include <cstdint>

// ExcitationShaper: segment-averaged params -> sigmoid/logspace maps -> gain ->
// fractional pluck comb -> time-varying RBJ low-pass biquad (TDF-II).
// Biquad parallelized as a blocked affine scan (2x2 matrix + vector compose).
// Comb gathers are served from an LDS tile (4096 samples + 256 halo, padded
// i+i/16 -> per-lane stride 17 words -> conflict-free) built with coalesced
// loads; seg ids travel as u16.

namespace {
constexpr int B = 32;
constexpr int T = 65536;
constexpr int MAXSEG = 2048;      // >> expected ~66 onsets/row (p=1e-3)
constexpr int L = 16;             // samples per scan chunk
constexpr int NC = T / L;         // 4096 chunks per row
constexpr int NCHT = B * NC;      // 131072 total chunks
constexpr int WV = 64;            // onset-count waves per row
constexpr int SPAN = T / WV;      // 1024 samples per wave
constexpr int SB = 4096;          // samples per compose/apply block
constexpr int HALO = 256;         // > max comb lag (p < 200 -> lag <= 201)

constexpr float MIN_W_C  = 0.00785398163397448279f; // 2*pi*20/16000 = pi/400
constexpr float LOG2_400 = 8.64385618977472436f;    // log2(pi / MIN_W)
constexpr float LOG2_20  = 4.32192809488736235f;    // log2(2.0/0.1)

__device__ __forceinline__ float sigmoid_precise(float v) {
  return 1.0f / (1.0f + expf(-v));
}
__device__ __forceinline__ int pad16(int i) { return i + (i >> 4); }
} // namespace

// ---- K1: count onsets per (row, wave-span) via ballot ----
__global__ void k_count(const int* __restrict__ onsets, int* __restrict__ cnt) {
  int gw = (blockIdx.x * blockDim.x + threadIdx.x) >> 6;
  int lane = threadIdx.x & 63;
  int b = gw / WV, wv = gw % WV;
  const int* po = onsets + b * T + wv * SPAN;
  int run = 0;
  for (int it = 0; it < SPAN / 64; ++it) {
    int o = po[it * 64 + lane];
    unsigned long long m = __ballot(o != 0);
    run += __popcll(m);
  }
  if (lane == 0) cnt[b * WV + wv] = run;
}

// ---- K2: exclusive scan of span counts per row (tiny) ----
__global__ void k_scanbase(const int* __restrict__ cnt, int* __restrict__ basep,
                           int* __restrict__ nseg) {
  int b = threadIdx.x;
  if (b < B) {
    int run = 0;
    for (int c = 0; c < WV; ++c) { basep[b * WV + c] = run; run += cnt[b * WV + c]; }
    nseg[b] = run;  // total onsets; segments = run+1
  }
}

// ---- K3: inclusive cumsum -> seg ids (u16, clamped); record onset positions ----
__global__ void k_segids(const int* __restrict__ onsets, const int* __restrict__ basep,
                         unsigned short* __restrict__ seg_ids, int* __restrict__ onsetPos) {
  int gw = (blockIdx.x * blockDim.x + threadIdx.x) >> 6;
  int lane = threadIdx.x & 63;
  int b = gw / WV, wv = gw % WV;
  const int rb = b * T;
  int t0 = wv * SPAN;
  int run = basep[b * WV + wv];
  unsigned long long bm = (1ull << lane) - 1ull;
  for (int it = 0; it < SPAN / 64; ++it) {
    int t = t0 + it * 64 + lane;
    int o = onsets[rb + t] != 0;
    unsigned long long m = __ballot(o);
    int sid = run + __popcll(m & bm) + o;   // inclusive cumsum
    seg_ids[rb + t] = (unsigned short)min(sid, MAXSEG - 1);
    if (o && sid <= MAXSEG) onsetPos[b * MAXSEG + sid - 1] = t;
    run += __popcll(m);
  }
}

// ---- K4: per-segment average + full coefficient precompute (precise math) ----
__global__ void k_segavg(const float* __restrict__ params, const int* __restrict__ onsetPos,
                         const int* __restrict__ nseg, float4* __restrict__ segc,
                         float* __restrict__ segd) {
  __shared__ float part[4][4];
  int b = blockIdx.x >> 6;   // 64 blocks grid-stride over segments per row
  int s0 = blockIdx.x & 63;
  int n = nseg[b];
  int tid = threadIdx.x;
  const float4* pp = (const float4*)params;  // [B][T] float4
  for (int s = s0; s <= n; s += 64) {
    int start = (s == 0) ? 0 : onsetPos[b * MAXSEG + min(s, MAXSEG) - 1];
    int end   = (s == n) ? T : onsetPos[b * MAXSEG + min(s, MAXSEG - 1)];
    float a0 = 0.f, a1 = 0.f, a2 = 0.f, a3 = 0.f;
    for (int t = start + tid; t < end; t += 256) {
      float4 pv = pp[b * T + t];
      a0 += pv.x; a1 += pv.y; a2 += pv.z; a3 += pv.w;
    }
    for (int off = 32; off; off >>= 1) {
      a0 += __shfl_down(a0, off); a1 += __shfl_down(a1, off);
      a2 += __shfl_down(a2, off); a3 += __shfl_down(a3, off);
    }
    if ((tid & 63) == 0) {
      int w = tid >> 6;
      part[w][0] = a0; part[w][1] = a1; part[w][2] = a2; part[w][3] = a3;
    }
    __syncthreads();
    if (tid == 0) {
      float t0 = 0.f, t1 = 0.f, t2 = 0.f, t3 = 0.f;
      for (int w = 0; w < 4; ++w) {
        t0 += part[w][0]; t1 += part[w][1]; t2 += part[w][2]; t3 += part[w][3];
      }
      float inv = 1.0f / (float)max(end - start, 1);
      float av0 = t0 * inv, av1 = t1 * inv, av2 = t2 * inv, av3 = t3 * inv;
      float dist = 0.1f * exp2f(sigmoid_precise(av0) * LOG2_20);
      float wv   = MIN_W_C * exp2f(sigmoid_precise(av1) * LOG2_400);
      float qv   = 0.1f * exp2f(sigmoid_precise(av2) * LOG2_20);
      float mu   = sigmoid_precise(av3);
      float sw = sinf(wv), cw = cosf(wv);
      float alpha = sw / (2.0f * qv);
      float a0c = 1.0f + alpha;
      float b0 = (1.0f - cw) / (2.0f * a0c);
      float na1 = 2.0f * cw / a0c;          // -a1
      float na2 = (alpha - 1.0f) / a0c;     // -a2
      int sl = min(s, MAXSEG - 1);
      segc[b * MAXSEG + sl] = make_float4(mu, b0, na1, na2);
      segd[b * MAXSEG + sl] = dist;
    }
    __syncthreads();
  }
}

// Shared build phase: stage xd = x*dist (with zeroed pre-row halo) and sid
// into padded LDS. Coalesced global reads; conflict-free LDS layout.
__device__ __forceinline__ void build_tile(int rb, int rs, int bs,
                                           const float* __restrict__ x,
                                           const unsigned short* __restrict__ seg,
                                           const float* __restrict__ segd,
                                           float* __restrict__ s_xd,
                                           int* __restrict__ s_sid) {
  int tid = threadIdx.x;
  for (int j = tid; j < SB + HALO; j += 256) {
    int tr = bs - HALO + j;           // row-relative sample index
    float v = 0.f;
    if (tr >= 0) {
      int s = (int)seg[rb + tr];
      v = x[rb + tr] * segd[rs + s];
    }
    s_xd[pad16(j)] = v;
  }
  for (int j = tid; j < SB; j += 256) {
    s_sid[pad16(j)] = (int)seg[rb + bs + j];
  }
  __syncthreads();
}

// Per-sample comb from LDS. Returns p0; outputs na1,na2 via segc.
__device__ __forceinline__ float comb_lds(int li, float ft, const float* __restrict__ s_xd,
                                          const int* __restrict__ s_sid, int rs,
                                          const float4* __restrict__ segc,
                                          float& na1, float& na2) {
  int s = s_sid[pad16(li)];
  float4 sc = segc[rs + s];          // {mu, b0, -a1, -a2}
  float p = ft * sc.x;
  float z = floorf(p);
  float alfa = p - z;
  int zi = min((int)z, HALO - 8);    // defensive; p < 200 in practice
  int i1 = li - zi - 1 + HALO;       // LDS coordinate (halo offset)
  float xl1 = s_xd[pad16(i1)];
  float xl2 = s_xd[pad16(i1 - 1)];
  float xc = s_xd[pad16(li + HALO)] - (1.f - alfa) * xl1 - alfa * xl2;
  na1 = sc.z; na2 = sc.w;
  return sc.y * xc;                  // p0 = b0 * xc
}

// ---- C1: compose per-chunk (L=16) affine transform, gathers from LDS ----
__global__ void k_compose(const float* __restrict__ f0, const float* __restrict__ x,
                          const unsigned short* __restrict__ seg,
                          const float4* __restrict__ segc,
                          const float* __restrict__ segd, float* __restrict__ ctb) {
  __shared__ float s_xd[4624];
  __shared__ int s_sid[4352];
  int blk = blockIdx.x;
  int b = blk >> 4, part = blk & 15;
  int rb = b * T, rs = b * MAXSEG;
  int bs = part * SB;
  build_tile(rb, rs, bs, x, seg, segd, s_xd, s_sid);

  int tid = threadIdx.x;
  int t0l = tid * 16;                 // local chunk start
  int g = blk * 256 + tid;            // global chunk id (matches b*NC + ...)
  const float4* f4 = (const float4*)(f0 + rb + bs + t0l);
  float A00 = 1.f, A01 = 0.f, A10 = 0.f, A11 = 1.f, d0 = 0.f, d1 = 0.f;
#pragma unroll
  for (int k = 0; k < 4; ++k) {
    float4 fv = f4[k];
    float fs[4] = {fv.x, fv.y, fv.z, fv.w};
#pragma unroll
    for (int q = 0; q < 4; ++q) {
      int li = t0l + k * 4 + q;
      float na1, na2;
      float p0 = comb_lds(li, fs[q], s_xd, s_sid, rs, segc, na1, na2);
      float c0v = p0 * (2.f + na1);
      float c1v = p0 * (1.f + na2);
      float nA00 = fmaf(na1, A00, A10);
      float nA01 = fmaf(na1, A01, A11);
      float nd0  = fmaf(na1, d0, d1 + c0v);
      float nA10 = na2 * A00;
      float nA11 = na2 * A01;
      float nd1  = fmaf(na2, d0, c1v);
      A00 = nA00; A01 = nA01; A10 = nA10; A11 = nA11; d0 = nd0; d1 = nd1;
    }
  }
  ctb[0 * NCHT + g] = A00; ctb[1 * NCHT + g] = A01;
  ctb[2 * NCHT + g] = A10; ctb[3 * NCHT + g] = A11;
  ctb[4 * NCHT + g] = d0;  ctb[5 * NCHT + g] = d1;
}

// ---- C2: per-row parallel scan over NC=4096 chunk transforms ----
__global__ void k_scanrows(const float* __restrict__ ctb, float* __restrict__ S1,
                           float* __restrict__ S2) {
  __shared__ float wagg[4][6];
  int b = blockIdx.x;
  int tid = threadIdx.x;
  int lane = tid & 63, w = tid >> 6;
  int base = b * NC + tid * 16;
  float A00 = 1.f, A01 = 0.f, A10 = 0.f, A11 = 1.f, d0 = 0.f, d1 = 0.f;
#pragma unroll
  for (int k = 0; k < 4; ++k) {
    float4 M00 = *(const float4*)(ctb + 0 * NCHT + base + k * 4);
    float4 M01 = *(const float4*)(ctb + 1 * NCHT + base + k * 4);
    float4 M10 = *(const float4*)(ctb + 2 * NCHT + base + k * 4);
    float4 M11 = *(const float4*)(ctb + 3 * NCHT + base + k * 4);
    float4 E0  = *(const float4*)(ctb + 4 * NCHT + base + k * 4);
    float4 E1  = *(const float4*)(ctb + 5 * NCHT + base + k * 4);
    float m00[4] = {M00.x, M00.y, M00.z, M00.w};
    float m01[4] = {M01.x, M01.y, M01.z, M01.w};
    float m10[4] = {M10.x, M10.y, M10.z, M10.w};
    float m11[4] = {M11.x, M11.y, M11.z, M11.w};
    float e0[4]  = {E0.x, E0.y, E0.z, E0.w};
    float e1[4]  = {E1.x, E1.y, E1.z, E1.w};
#pragma unroll
    for (int q = 0; q < 4; ++q) {
      float nA00 = fmaf(m00[q], A00, m01[q] * A10);
      float nA01 = fmaf(m00[q], A01, m01[q] * A11);
      float nA10 = fmaf(m10[q], A00, m11[q] * A10);
      float nA11 = fmaf(m10[q], A01, m11[q] * A11);
      float nd0  = fmaf(m00[q], d0, fmaf(m01[q], d1, e0[q]));
      float nd1  = fmaf(m10[q], d0, fmaf(m11[q], d1, e1[q]));
      A00 = nA00; A01 = nA01; A10 = nA10; A11 = nA11; d0 = nd0; d1 = nd1;
    }
  }
#pragma unroll
  for (int off = 1; off < 64; off <<= 1) {
    float P00 = __shfl_up(A00, off), P01 = __shfl_up(A01, off);
    float P10 = __shfl_up(A10, off), P11 = __shfl_up(A11, off);
    float Pd0 = __shfl_up(d0, off),  Pd1 = __shfl_up(d1, off);
    if (lane >= off) {
      float nA00 = fmaf(A00, P00, A01 * P10);
      float nA01 = fmaf(A00, P01, A01 * P11);
      float nA10 = fmaf(A10, P00, A11 * P10);
      float nA11 = fmaf(A10, P01, A11 * P11);
      float nd0  = fmaf(A00, Pd0, fmaf(A01, Pd1, d0));
      float nd1  = fmaf(A10, Pd0, fmaf(A11, Pd1, d1));
      A00 = nA00; A01 = nA01; A10 = nA10; A11 = nA11; d0 = nd0; d1 = nd1;
    }
  }
  if (lane == 63) {
    wagg[w][0] = A00; wagg[w][1] = A01; wagg[w][2] = A10;
    wagg[w][3] = A11; wagg[w][4] = d0;  wagg[w][5] = d1;
  }
  __syncthreads();
  float E00 = __shfl_up(A00, 1), E01 = __shfl_up(A01, 1);
  float E10 = __shfl_up(A10, 1), E11 = __shfl_up(A11, 1);
  float Ed0 = __shfl_up(d0, 1),  Ed1 = __shfl_up(d1, 1);
  if (lane == 0) { E00 = 1.f; E01 = 0.f; E10 = 0.f; E11 = 1.f; Ed0 = 0.f; Ed1 = 0.f; }
  float P00 = 1.f, P01 = 0.f, P10 = 0.f, P11 = 1.f, Pd0 = 0.f, Pd1 = 0.f;
  for (int i = 0; i < w; ++i) {
    float W00 = wagg[i][0], W01 = wagg[i][1], W10 = wagg[i][2];
    float W11 = wagg[i][3], Wd0 = wagg[i][4], Wd1 = wagg[i][5];
    float n00 = fmaf(W00, P00, W01 * P10);
    float n01 = fmaf(W00, P01, W01 * P11);
    float n10 = fmaf(W10, P00, W11 * P10);
    float n11 = fmaf(W10, P01, W11 * P11);
    float nd0 = fmaf(W00, Pd0, fmaf(W01, Pd1, Wd0));
    float nd1 = fmaf(W10, Pd0, fmaf(W11, Pd1, Wd1));
    P00 = n00; P01 = n01; P10 = n10; P11 = n11; Pd0 = nd0; Pd1 = nd1;
  }
  float s1 = fmaf(E00, Pd0, fmaf(E01, Pd1, Ed0));
  float s2 = fmaf(E10, Pd0, fmaf(E11, Pd1, Ed1));
#pragma unroll
  for (int k = 0; k < 4; ++k) {
    float4 M00 = *(const float4*)(ctb + 0 * NCHT + base + k * 4);
    float4 M01 = *(const float4*)(ctb + 1 * NCHT + base + k * 4);
    float4 M10 = *(const float4*)(ctb + 2 * NCHT + base + k * 4);
    float4 M11 = *(const float4*)(ctb + 3 * NCHT + base + k * 4);
    float4 E0  = *(const float4*)(ctb + 4 * NCHT + base + k * 4);
    float4 E1  = *(const float4*)(ctb + 5 * NCHT + base + k * 4);
    float m00[4] = {M00.x, M00.y, M00.z, M00.w};
    float m01[4] = {M01.x, M01.y, M01.z, M01.w};
    float m10[4] = {M10.x, M10.y, M10.z, M10.w};
    float m11[4] = {M11.x, M11.y, M11.z, M11.w};
    float e0[4]  = {E0.x, E0.y, E0.z, E0.w};
    float e1[4]  = {E1.x, E1.y, E1.z, E1.w};
    float o1[4], o2[4];
#pragma unroll
    for (int q = 0; q < 4; ++q) {
      o1[q] = s1; o2[q] = s2;
      float t1 = fmaf(m00[q], s1, fmaf(m01[q], s2, e0[q]));
      float t2 = fmaf(m10[q], s1, fmaf(m11[q], s2, e1[q]));
      s1 = t1; s2 = t2;
    }
    *(float4*)(S1 + base + k * 4) = make_float4(o1[0], o1[1], o1[2], o1[3]);
    *(float4*)(S2 + base + k * 4) = make_float4(o2[0], o2[1], o2[2], o2[3]);
  }
}

// ---- C3: re-apply recurrence from chunk-start state, gathers from LDS ----
__global__ void k_apply(const float* __restrict__ f0, const float* __restrict__ x,
                        const unsigned short* __restrict__ seg,
                        const float4* __restrict__ segc,
                        const float* __restrict__ segd, const float* __restrict__ S1,
                        const float* __restrict__ S2, float* __restrict__ out) {
  __shared__ float s_xd[4624];
  __shared__ int s_sid[4352];
  int blk = blockIdx.x;
  int b = blk >> 4, part = blk & 15;
  int rb = b * T, rs = b * MAXSEG;
  int bs = part * SB;
  build_tile(rb, rs, bs, x, seg, segd, s_xd, s_sid);

  int tid = threadIdx.x;
  int t0l = tid * 16;
  int g = blk * 256 + tid;
  const float4* f4 = (const float4*)(f0 + rb + bs + t0l);
  float4* o4 = (float4*)(out + rb + bs + t0l);
  float s1 = S1[g], s2 = S2[g];
#pragma unroll
  for (int k = 0; k < 4; ++k) {
    float4 fv = f4[k];
    float fs[4] = {fv.x, fv.y, fv.z, fv.w};
    float ys[4];
#pragma unroll
    for (int q = 0; q < 4; ++q) {
      int li = t0l + k * 4 + q;
      float na1, na2;
      float p0 = comb_lds(li, fs[q], s_xd, s_sid, rs, segc, na1, na2);
      float y = p0 + s1;
      ys[q] = y;
      float ns1 = fmaf(na1, y, fmaf(2.f, p0, s2));
      float ns2 = fmaf(na2, y, p0);
      s1 = ns1; s2 = ns2;
    }
    o4[k] = make_float4(ys[0], ys[1], ys[2], ys[3]);
  }
}

extern "C" void kernel_launch(void* const* d_in, const int* in_sizes, int n_in,
                              void* d_out, int out_size, void* d_ws, size_t ws_size,
                              hipStream_t stream) {
  const float* f0     = (const float*)d_in[0];
  const float* x      = (const float*)d_in[1];
  const float* params = (const float*)d_in[2];
  const int*   onsets = (const int*)d_in[3];
  float* out = (float*)d_out;

  char* w = (char*)d_ws;
  auto alloc = [&](size_t bytes) -> void* {
    void* p = (void*)w;
    w += (bytes + 255) & ~(size_t)255;
    return p;
  };
  unsigned short* seg_ids = (unsigned short*)alloc(sizeof(unsigned short) * B * T);
  int*    cnt      = (int*)alloc(sizeof(int) * B * WV);
  int*    basep    = (int*)alloc(sizeof(int) * B * WV);
  int*    nseg     = (int*)alloc(sizeof(int) * B);
  int*    onsetPos = (int*)alloc(sizeof(int) * B * MAXSEG);
  float4* segc     = (float4*)alloc(sizeof(float4) * B * MAXSEG);
  float*  segd     = (float*)alloc(sizeof(float) * B * MAXSEG);
  float*  ctb      = (float*)alloc(sizeof(float) * 6 * NCHT);
  float*  S1       = (float*)alloc(sizeof(float) * NCHT);
  float*  S2       = (float*)alloc(sizeof(float) * NCHT);
  (void)in_sizes; (void)n_in; (void)out_size; (void)ws_size;

  k_count   <<<512, 256, 0, stream>>>(onsets, cnt);
  k_scanbase<<<1, 64, 0, stream>>>(cnt, basep, nseg);
  k_segids  <<<512, 256, 0, stream>>>(onsets, basep, seg_ids, onsetPos);
  k_segavg  <<<B * 64, 256, 0, stream>>>(params, onsetPos, nseg, segc, segd);
  k_compose <<<NCHT / 256, 256, 0, stream>>>(f0, x, seg_ids, segc, segd, ctb);
  k_scanrows<<<B, 256, 0, stream>>>(ctb, S1, S2);
  k_apply   <<<NCHT / 256, 256, 0, stream>>>(f0, x, seg_ids, segc, segd, S1, S2, out);
}